// Round 4
// baseline (438.145 us; speedup 1.0000x reference)
//
#include <hip/hip_runtime.h>
#include <math.h>

#ifndef M_PI
#define M_PI 3.14159265358979323846
#endif

#define N_FFT       512
#define N_BINS      257
#define N_FILTERS   128
#define OUTPUT_SIZE 262144
#define N_TIMESTEPS 128

// ---- ordered-uint64 encoding for deterministic double atomic min/max ----
__device__ __forceinline__ unsigned long long enc_d(double f) {
    unsigned long long u = (unsigned long long)__double_as_longlong(f);
    return (u & 0x8000000000000000ull) ? ~u : (u | 0x8000000000000000ull);
}
__device__ __forceinline__ double dec_d(unsigned long long e) {
    unsigned long long u = (e & 0x8000000000000000ull) ? (e ^ 0x8000000000000000ull) : ~e;
    return __longlong_as_double((long long)u);
}

// ============================================================================
// K1: front-end, FULL FP64. 512 threads; DFT split into 2 half-sums per bin
// (514 work items) with direct twiddle indexing m=(b*n)&511 + unroll-8 so
// many independent ds_reads are in flight (old recurrence index was
// latency-serial at ~120 cyc/read).
//   mag  = fp32(|DFT|)        (the reference's .astype(float32))
//   cochlear/hair/adapted all fp64  -> adapted (double) in ws
// ============================================================================
__global__ __launch_bounds__(512) void k1_frontend(
    const float* __restrict__ audio, const float* __restrict__ fb,
    const float* __restrict__ adapt, double* __restrict__ adapted,
    unsigned long long* __restrict__ minmax)
{
    __shared__ double tw_c[N_FFT];
    __shared__ double tw_s[N_FFT];
    __shared__ double aud[N_FFT];
    __shared__ double re_p[2 * N_BINS];   // [bin][half]
    __shared__ double im_p[2 * N_BINS];
    __shared__ float  mag[N_BINS];

    const int tid = threadIdx.x;

    if (tid < N_FFT) {
        double ang = (-2.0 * M_PI * (double)tid) / (double)N_FFT;
        double s, c;
        sincos(ang, &s, &c);
        tw_c[tid] = c;
        tw_s[tid] = s;
        aud[tid] = (double)audio[tid];   // rfft(n=512): first 512 samples
    }
    __syncthreads();

    // 514 items: item w -> bin w>>1, half w&1 (only threads 0,1 loop twice)
    for (int w = tid; w < 2 * N_BINS; w += 512) {
        const int b  = w >> 1;
        const int n0 = (w & 1) * 256;
        double re = 0.0, im = 0.0;
        #pragma unroll 8
        for (int j = 0; j < 256; ++j) {
            const int n = n0 + j;
            const int m = (b * n) & (N_FFT - 1);
            const double a = aud[n];
            re += a * tw_c[m];
            im += a * tw_s[m];
        }
        re_p[w] = re;
        im_p[w] = im;
    }
    __syncthreads();

    if (tid < N_BINS) {
        const double re = re_p[2 * tid] + re_p[2 * tid + 1]; // deterministic order
        const double im = im_p[2 * tid] + im_p[2 * tid + 1];
        mag[tid] = (float)sqrt(re * re + im * im);           // .astype(float32)
    }
    __syncthreads();

    if (tid < N_FILTERS) {
        double acc = 0.0;
        const float* row = fb + tid * N_BINS;
        #pragma unroll 4
        for (int j = 0; j < N_BINS; ++j)
            acc += (double)row[j] * (double)mag[j];
        const double x = acc + 1e-6;               // + LATENCY_EPSILON
        const double p = pow(x, 0.3);
        const double a = p - (double)adapt[tid] * 0.5;
        adapted[tid] = a > 0.0 ? a : 0.0;          // relu
    }
    if (tid == 0) {
        minmax[0] = 0xFFFFFFFFFFFFFFFFull;  // min slot
        minmax[1] = 0ull;                   // max slot
    }
}

// ============================================================================
// K2: activity = W @ adapted + b (fp64), COALESCED.
//   2 rows per wave per iteration: lane -> (row = lane&1, chunk = lane>>1).
//   Wave-load = 64 consecutive float4 = 1 KB contiguous (was 64 lines at
//   512-B stride). Per-lane adapted chunk is loop-invariant -> registers.
//   Row dot finished with 5 parity-preserving xor-butterflies (offs 2..32).
//   1024 blocks x 256 thr = 4096 waves x 64 rows (32 iters).
// ============================================================================
__global__ __launch_bounds__(256) void k2_gemv(
    const float4* __restrict__ W4, const float* __restrict__ bias,
    const double* __restrict__ adapted, double* __restrict__ activity,
    unsigned long long* __restrict__ minmax)
{
    const int tid  = threadIdx.x;
    const int lane = tid & 63;
    const int gwave = blockIdx.x * 4 + (tid >> 6);      // 0..4095
    const int base_row = gwave * 64;

    // loop-invariant adapted chunk for this lane: elements 4c..4c+3, c=lane>>1
    const int kk = (lane >> 1) * 4;
    const double A0 = adapted[kk + 0];
    const double A1 = adapted[kk + 1];
    const double A2 = adapted[kk + 2];
    const double A3 = adapted[kk + 3];

    // lane's slot inside the wave's contiguous 1-KB (2-row) burst
    const int perm = (lane & 1) * 32 + (lane >> 1);
    const float4* wp = W4 + (size_t)base_row * (N_FILTERS / 4) + perm;

    double mn = 1e300, mx = -1e300;

    #pragma unroll 4
    for (int it = 0; it < 32; ++it) {
        const float4 w = wp[it * 64];
        double acc = (double)w.x * A0 + (double)w.y * A1
                   + (double)w.z * A2 + (double)w.w * A3;
        acc += __shfl_xor(acc, 2);
        acc += __shfl_xor(acc, 4);
        acc += __shfl_xor(acc, 8);
        acc += __shfl_xor(acc, 16);
        acc += __shfl_xor(acc, 32);
        // every lane of parity p now holds the full dot of row base+2it+p
        const int row = base_row + it * 2 + (lane & 1);
        const double a = acc + (double)bias[row];
        if (lane < 2) activity[row] = a;
        mn = fmin(mn, a);
        mx = fmax(mx, a);
    }

    // wave-wide min/max (duplicates across lanes are harmless)
    #pragma unroll
    for (int off = 1; off < 64; off <<= 1) {
        mn = fmin(mn, __shfl_xor(mn, off));
        mx = fmax(mx, __shfl_xor(mx, off));
    }
    if (lane == 0) {
        atomicMin(&minmax[0], enc_d(mn));
        atomicMax(&minmax[1], enc_d(mx));
    }
}

// ============================================================================
// K3: latency coding + spike-matrix write (int32 out). fp64 quantization:
//   norm = (a-amin)/((amax-amin)+1e-6); lat = (int)((1-norm)*127); fire = norm>0.05
//   t-loop split over gridDim.y=4 -> 1024 blocks (4/CU) for store throughput.
//   int4 stores, 1 KB/wave/store, every element written.
// ============================================================================
__global__ __launch_bounds__(256) void k3_spikes(
    const double* __restrict__ activity,
    const unsigned long long* __restrict__ minmax,
    int4* __restrict__ out4)
{
    const int tid = blockIdx.x * 256 + threadIdx.x;  // 0..65535
    const double amin = dec_d(minmax[0]);
    const double amax = dec_d(minmax[1]);
    const double denom = (amax - amin) + 1e-6;

    const double nx = (activity[4 * tid + 0] - amin) / denom;
    const double ny = (activity[4 * tid + 1] - amin) / denom;
    const double nz = (activity[4 * tid + 2] - amin) / denom;
    const double nw = (activity[4 * tid + 3] - amin) / denom;

    const int lx = (int)((1.0 - nx) * 127.0);
    const int ly = (int)((1.0 - ny) * 127.0);
    const int lz = (int)((1.0 - nz) * 127.0);
    const int lw = (int)((1.0 - nw) * 127.0);

    const int vx = (nx > 0.05) ? 1 : 0;
    const int vy = (ny > 0.05) ? 1 : 0;
    const int vz = (nz > 0.05) ? 1 : 0;
    const int vw = (nw > 0.05) ? 1 : 0;

    const int t0 = blockIdx.y * (N_TIMESTEPS / 4);
    #pragma unroll 8
    for (int t = t0; t < t0 + N_TIMESTEPS / 4; ++t) {
        int4 v;
        v.x = (lx == t) ? vx : 0;
        v.y = (ly == t) ? vy : 0;
        v.z = (lz == t) ? vz : 0;
        v.w = (lw == t) ? vw : 0;
        out4[(size_t)t * (OUTPUT_SIZE / 4) + tid] = v;
    }
}

// ============================================================================
extern "C" void kernel_launch(void* const* d_in, const int* in_sizes, int n_in,
                              void* d_out, int out_size, void* d_ws, size_t ws_size,
                              hipStream_t stream) {
    (void)in_sizes; (void)n_in; (void)out_size; (void)ws_size;

    const float* audio = (const float*)d_in[0];   // [16000]
    const float* fb    = (const float*)d_in[1];   // [128, 257]
    const float* W     = (const float*)d_in[2];   // [262144, 128]
    const float* bias  = (const float*)d_in[3];   // [262144]
    const float* adapt = (const float*)d_in[4];   // [128]
    int* out = (int*)d_out;                       // [128, 262144] bool -> int32

    double* activity = (double*)d_ws;                              // 262144 f64
    double* adapted  = activity + OUTPUT_SIZE;                     // 128 f64
    unsigned long long* minmax =
        (unsigned long long*)(adapted + N_FILTERS);                // 2 u64

    k1_frontend<<<1, 512, 0, stream>>>(audio, fb, adapt, adapted, minmax);
    k2_gemv<<<OUTPUT_SIZE / 256, 256, 0, stream>>>(
        (const float4*)W, bias, adapted, activity, minmax);
    k3_spikes<<<dim3(OUTPUT_SIZE / 4 / 256, 4), 256, 0, stream>>>(
        activity, minmax, (int4*)out);
}

// Round 6
// 341.225 us; speedup vs baseline: 1.2840x; 1.2840x over previous
//
#include <hip/hip_runtime.h>
#include <math.h>

#ifndef M_PI
#define M_PI 3.14159265358979323846
#endif

#define N_FFT       512
#define N_BINS      257
#define N_FILTERS   128
#define OUTPUT_SIZE 262144
#define N_TIMESTEPS 128

// native vector type for __builtin_nontemporal_store (HIP int4 is a class)
typedef int int4v __attribute__((ext_vector_type(4)));

// ---- ordered-uint64 encoding for deterministic double atomic min/max ----
__device__ __forceinline__ unsigned long long enc_d(double f) {
    unsigned long long u = (unsigned long long)__double_as_longlong(f);
    return (u & 0x8000000000000000ull) ? ~u : (u | 0x8000000000000000ull);
}
__device__ __forceinline__ double dec_d(unsigned long long e) {
    unsigned long long u = (e & 0x8000000000000000ull) ? (e ^ 0x8000000000000000ull) : ~e;
    return __longlong_as_double((long long)u);
}

// ============================================================================
// K1: front-end, FULL FP64 (verified round 4). 512 threads; DFT as 2
// half-sums per bin, direct twiddle index + unroll-8 for ds_read ILP.
// ============================================================================
__global__ __launch_bounds__(512) void k1_frontend(
    const float* __restrict__ audio, const float* __restrict__ fb,
    const float* __restrict__ adapt, double* __restrict__ adapted,
    unsigned long long* __restrict__ minmax)
{
    __shared__ double tw_c[N_FFT];
    __shared__ double tw_s[N_FFT];
    __shared__ double aud[N_FFT];
    __shared__ double re_p[2 * N_BINS];
    __shared__ double im_p[2 * N_BINS];
    __shared__ float  mag[N_BINS];

    const int tid = threadIdx.x;

    if (tid < N_FFT) {
        double ang = (-2.0 * M_PI * (double)tid) / (double)N_FFT;
        double s, c;
        sincos(ang, &s, &c);
        tw_c[tid] = c;
        tw_s[tid] = s;
        aud[tid] = (double)audio[tid];   // rfft(n=512): first 512 samples
    }
    __syncthreads();

    for (int w = tid; w < 2 * N_BINS; w += 512) {
        const int b  = w >> 1;
        const int n0 = (w & 1) * 256;
        double re = 0.0, im = 0.0;
        #pragma unroll 8
        for (int j = 0; j < 256; ++j) {
            const int n = n0 + j;
            const int m = (b * n) & (N_FFT - 1);
            const double a = aud[n];
            re += a * tw_c[m];
            im += a * tw_s[m];
        }
        re_p[w] = re;
        im_p[w] = im;
    }
    __syncthreads();

    if (tid < N_BINS) {
        const double re = re_p[2 * tid] + re_p[2 * tid + 1]; // deterministic
        const double im = im_p[2 * tid] + im_p[2 * tid + 1];
        mag[tid] = (float)sqrt(re * re + im * im);           // .astype(float32)
    }
    __syncthreads();

    if (tid < N_FILTERS) {
        double acc = 0.0;
        const float* row = fb + tid * N_BINS;
        #pragma unroll 4
        for (int j = 0; j < N_BINS; ++j)
            acc += (double)row[j] * (double)mag[j];
        const double x = acc + 1e-6;               // + LATENCY_EPSILON
        const double p = pow(x, 0.3);
        const double a = p - (double)adapt[tid] * 0.5;
        adapted[tid] = a > 0.0 ? a : 0.0;          // relu
    }
    if (tid == 0) {
        minmax[0] = 0xFFFFFFFFFFFFFFFFull;  // min slot
        minmax[1] = 0ull;                   // max slot
    }
}

// ============================================================================
// K2: activity = W @ adapted + b (fp64) — VERIFIED round-3 structure.
//   One thread per row, 32 independent float4 loads (unroll 8), sequential
//   fp64 accumulate (deterministic, matched ref with absmax 0). NO per-
//   iteration cross-lane ops (round-4's 5x shfl_xor/iter chain was the
//   137-us latency bomb: VALUBusy 3.9%). L1/L2 absorb the 512-B-stride
//   line reuse; HBM/L3 see each line once. Block min/max via LDS tree,
//   one atomic pair per block.
// ============================================================================
__global__ __launch_bounds__(256) void k2_gemv(
    const float4* __restrict__ W4, const float* __restrict__ bias,
    const double* __restrict__ adapted, double* __restrict__ activity,
    unsigned long long* __restrict__ minmax)
{
    __shared__ double ad[N_FILTERS];
    __shared__ double red_min[256];
    __shared__ double red_max[256];

    const int tid = threadIdx.x;
    if (tid < N_FILTERS) ad[tid] = adapted[tid];
    __syncthreads();

    const int row = blockIdx.x * 256 + tid;
    const float4* wrow = W4 + (size_t)row * (N_FILTERS / 4);

    double acc = 0.0;
    #pragma unroll 8
    for (int j = 0; j < N_FILTERS / 4; ++j) {
        float4 w = wrow[j];
        const int k = j * 4;
        acc += (double)w.x * ad[k];
        acc += (double)w.y * ad[k + 1];
        acc += (double)w.z * ad[k + 2];
        acc += (double)w.w * ad[k + 3];
    }
    double a = acc + (double)bias[row];
    activity[row] = a;

    red_min[tid] = a;
    red_max[tid] = a;
    __syncthreads();
    for (int s = 128; s > 0; s >>= 1) {
        if (tid < s) {
            red_min[tid] = fmin(red_min[tid], red_min[tid + s]);
            red_max[tid] = fmax(red_max[tid], red_max[tid + s]);
        }
        __syncthreads();
    }
    if (tid == 0) {
        atomicMin(&minmax[0], enc_d(red_min[0]));
        atomicMax(&minmax[1], enc_d(red_max[0]));
    }
}

// ============================================================================
// K3: latency coding + spike-matrix write (int32 out), fp64 quantization.
//   t-loop split over gridDim.y=4 -> 1024 blocks. NONTEMPORAL 16-B stores
//   (native ext_vector int4v): the 134 MB output shouldn't evict W from L3
//   (FETCH_SIZE showed W is partially L3-resident across iterations).
// ============================================================================
__global__ __launch_bounds__(256) void k3_spikes(
    const double* __restrict__ activity,
    const unsigned long long* __restrict__ minmax,
    int4v* __restrict__ out4)
{
    const int tid = blockIdx.x * 256 + threadIdx.x;  // 0..65535
    const double amin = dec_d(minmax[0]);
    const double amax = dec_d(minmax[1]);
    const double denom = (amax - amin) + 1e-6;

    const double nx = (activity[4 * tid + 0] - amin) / denom;
    const double ny = (activity[4 * tid + 1] - amin) / denom;
    const double nz = (activity[4 * tid + 2] - amin) / denom;
    const double nw = (activity[4 * tid + 3] - amin) / denom;

    const int lx = (int)((1.0 - nx) * 127.0);
    const int ly = (int)((1.0 - ny) * 127.0);
    const int lz = (int)((1.0 - nz) * 127.0);
    const int lw = (int)((1.0 - nw) * 127.0);

    const int vx = (nx > 0.05) ? 1 : 0;
    const int vy = (ny > 0.05) ? 1 : 0;
    const int vz = (nz > 0.05) ? 1 : 0;
    const int vw = (nw > 0.05) ? 1 : 0;

    const int t0 = blockIdx.y * (N_TIMESTEPS / 4);
    #pragma unroll 8
    for (int t = t0; t < t0 + N_TIMESTEPS / 4; ++t) {
        int4v v;
        v.x = (lx == t) ? vx : 0;
        v.y = (ly == t) ? vy : 0;
        v.z = (lz == t) ? vz : 0;
        v.w = (lw == t) ? vw : 0;
        __builtin_nontemporal_store(v, &out4[(size_t)t * (OUTPUT_SIZE / 4) + tid]);
    }
}

// ============================================================================
extern "C" void kernel_launch(void* const* d_in, const int* in_sizes, int n_in,
                              void* d_out, int out_size, void* d_ws, size_t ws_size,
                              hipStream_t stream) {
    (void)in_sizes; (void)n_in; (void)out_size; (void)ws_size;

    const float* audio = (const float*)d_in[0];   // [16000]
    const float* fb    = (const float*)d_in[1];   // [128, 257]
    const float* W     = (const float*)d_in[2];   // [262144, 128]
    const float* bias  = (const float*)d_in[3];   // [262144]
    const float* adapt = (const float*)d_in[4];   // [128]
    int* out = (int*)d_out;                       // [128, 262144] bool -> int32

    double* activity = (double*)d_ws;                              // 262144 f64
    double* adapted  = activity + OUTPUT_SIZE;                     // 128 f64
    unsigned long long* minmax =
        (unsigned long long*)(adapted + N_FILTERS);                // 2 u64

    k1_frontend<<<1, 512, 0, stream>>>(audio, fb, adapt, adapted, minmax);
    k2_gemv<<<OUTPUT_SIZE / 256, 256, 0, stream>>>(
        (const float4*)W, bias, adapted, activity, minmax);
    k3_spikes<<<dim3(OUTPUT_SIZE / 4 / 256, 4), 256, 0, stream>>>(
        activity, minmax, (int4v*)out);
}

// Round 7
// 310.876 us; speedup vs baseline: 1.4094x; 1.0976x over previous
//
#include <hip/hip_runtime.h>
#include <math.h>

#ifndef M_PI
#define M_PI 3.14159265358979323846
#endif

#define N_FFT       512
#define N_BINS      257
#define N_FILTERS   128
#define OUTPUT_SIZE 262144
#define N_TIMESTEPS 128

// native vector type for __builtin_nontemporal_store (HIP int4 is a class)
typedef int int4v __attribute__((ext_vector_type(4)));

// ---- ordered-uint64 encoding for deterministic double atomic min/max ----
__device__ __forceinline__ unsigned long long enc_d(double f) {
    unsigned long long u = (unsigned long long)__double_as_longlong(f);
    return (u & 0x8000000000000000ull) ? ~u : (u | 0x8000000000000000ull);
}
__device__ __forceinline__ double dec_d(unsigned long long e) {
    unsigned long long u = (e & 0x8000000000000000ull) ? (e ^ 0x8000000000000000ull) : ~e;
    return __longlong_as_double((long long)u);
}

// ============================================================================
// K1a: DFT, one block per bin (257 blocks x 64 threads).
//   Round-6 k1 was a single block on one CU: 91 us, 0.05% occupancy, 39k LDS
//   conflict cycles. Same math, 257-way parallel: lane accumulates 8 samples
//   (sequential j), twiddles via the SAME fp64 sincos(-2*pi*m/512) formula
//   (bit-identical values to the old table), deterministic LDS tree reduce.
//   mag[b] = float(|DFT_b|)   (the reference's .astype(float32))
// ============================================================================
__global__ __launch_bounds__(64) void k1a_dft(
    const float* __restrict__ audio, float* __restrict__ mag)
{
    __shared__ double sre[64];
    __shared__ double sim[64];

    const int b    = blockIdx.x;     // bin 0..256
    const int lane = threadIdx.x;    // 0..63

    double re = 0.0, im = 0.0;
    #pragma unroll
    for (int j = 0; j < 8; ++j) {
        const int n = lane * 8 + j;              // rfft(n=512): first 512 samples
        const int m = (b * n) & (N_FFT - 1);
        double s, c;
        sincos((-2.0 * M_PI * (double)m) / (double)N_FFT, &s, &c);
        const double a = (double)audio[n];
        re += a * c;
        im += a * s;
    }
    sre[lane] = re;
    sim[lane] = im;
    __syncthreads();
    #pragma unroll
    for (int s = 32; s > 0; s >>= 1) {
        if (lane < s) {
            sre[lane] += sre[lane + s];
            sim[lane] += sim[lane + s];
        }
        __syncthreads();
    }
    if (lane == 0)
        mag[b] = (float)sqrt(sre[0] * sre[0] + sim[0] * sim[0]);
}

// ============================================================================
// K1b: post-DFT front-end (1 block x 256 threads) — verified numerics:
//   cochlear = fb @ mag (sequential fp64), hair = pow(cochlear+1e-6, 0.3),
//   adapted = relu(hair - adapt*0.5); init minmax slots.
// ============================================================================
__global__ __launch_bounds__(256) void k1b_post(
    const float* __restrict__ fb, const float* __restrict__ mag,
    const float* __restrict__ adapt, double* __restrict__ adapted,
    unsigned long long* __restrict__ minmax)
{
    __shared__ float magl[N_BINS];
    const int tid = threadIdx.x;

    for (int j = tid; j < N_BINS; j += 256) magl[j] = mag[j];
    __syncthreads();

    if (tid < N_FILTERS) {
        double acc = 0.0;
        const float* row = fb + tid * N_BINS;
        #pragma unroll 4
        for (int j = 0; j < N_BINS; ++j)
            acc += (double)row[j] * (double)magl[j];
        const double x = acc + 1e-6;               // + LATENCY_EPSILON
        const double p = pow(x, 0.3);
        const double a = p - (double)adapt[tid] * 0.5;
        adapted[tid] = a > 0.0 ? a : 0.0;          // relu
    }
    if (tid == 0) {
        minmax[0] = 0xFFFFFFFFFFFFFFFFull;  // min slot
        minmax[1] = 0ull;                   // max slot
    }
}

// ============================================================================
// K2: activity = W @ adapted + b (fp64) — VERIFIED round-3 structure.
//   One thread per row, 32 independent float4 loads (unroll 8), sequential
//   fp64 accumulate. No per-iteration cross-lane ops (round-4's shfl chain
//   was a 137-us latency bomb). L1/L2 absorb the 512-B-stride line reuse.
//   Block min/max via LDS tree, one atomic pair per block.
// ============================================================================
__global__ __launch_bounds__(256) void k2_gemv(
    const float4* __restrict__ W4, const float* __restrict__ bias,
    const double* __restrict__ adapted, double* __restrict__ activity,
    unsigned long long* __restrict__ minmax)
{
    __shared__ double ad[N_FILTERS];
    __shared__ double red_min[256];
    __shared__ double red_max[256];

    const int tid = threadIdx.x;
    if (tid < N_FILTERS) ad[tid] = adapted[tid];
    __syncthreads();

    const int row = blockIdx.x * 256 + tid;
    const float4* wrow = W4 + (size_t)row * (N_FILTERS / 4);

    double acc = 0.0;
    #pragma unroll 8
    for (int j = 0; j < N_FILTERS / 4; ++j) {
        float4 w = wrow[j];
        const int k = j * 4;
        acc += (double)w.x * ad[k];
        acc += (double)w.y * ad[k + 1];
        acc += (double)w.z * ad[k + 2];
        acc += (double)w.w * ad[k + 3];
    }
    double a = acc + (double)bias[row];
    activity[row] = a;

    red_min[tid] = a;
    red_max[tid] = a;
    __syncthreads();
    for (int s = 128; s > 0; s >>= 1) {
        if (tid < s) {
            red_min[tid] = fmin(red_min[tid], red_min[tid + s]);
            red_max[tid] = fmax(red_max[tid], red_max[tid + s]);
        }
        __syncthreads();
    }
    if (tid == 0) {
        atomicMin(&minmax[0], enc_d(red_min[0]));
        atomicMax(&minmax[1], enc_d(red_max[0]));
    }
}

// ============================================================================
// K3: latency coding + spike-matrix write (int32 out), fp64 quantization.
//   t-loop split over gridDim.y=4 -> 1024 blocks. Nontemporal 16-B stores
//   (keep W L3-resident across graph iterations).
// ============================================================================
__global__ __launch_bounds__(256) void k3_spikes(
    const double* __restrict__ activity,
    const unsigned long long* __restrict__ minmax,
    int4v* __restrict__ out4)
{
    const int tid = blockIdx.x * 256 + threadIdx.x;  // 0..65535
    const double amin = dec_d(minmax[0]);
    const double amax = dec_d(minmax[1]);
    const double denom = (amax - amin) + 1e-6;

    const double nx = (activity[4 * tid + 0] - amin) / denom;
    const double ny = (activity[4 * tid + 1] - amin) / denom;
    const double nz = (activity[4 * tid + 2] - amin) / denom;
    const double nw = (activity[4 * tid + 3] - amin) / denom;

    const int lx = (int)((1.0 - nx) * 127.0);
    const int ly = (int)((1.0 - ny) * 127.0);
    const int lz = (int)((1.0 - nz) * 127.0);
    const int lw = (int)((1.0 - nw) * 127.0);

    const int vx = (nx > 0.05) ? 1 : 0;
    const int vy = (ny > 0.05) ? 1 : 0;
    const int vz = (nz > 0.05) ? 1 : 0;
    const int vw = (nw > 0.05) ? 1 : 0;

    const int t0 = blockIdx.y * (N_TIMESTEPS / 4);
    #pragma unroll 8
    for (int t = t0; t < t0 + N_TIMESTEPS / 4; ++t) {
        int4v v;
        v.x = (lx == t) ? vx : 0;
        v.y = (ly == t) ? vy : 0;
        v.z = (lz == t) ? vz : 0;
        v.w = (lw == t) ? vw : 0;
        __builtin_nontemporal_store(v, &out4[(size_t)t * (OUTPUT_SIZE / 4) + tid]);
    }
}

// ============================================================================
extern "C" void kernel_launch(void* const* d_in, const int* in_sizes, int n_in,
                              void* d_out, int out_size, void* d_ws, size_t ws_size,
                              hipStream_t stream) {
    (void)in_sizes; (void)n_in; (void)out_size; (void)ws_size;

    const float* audio = (const float*)d_in[0];   // [16000]
    const float* fb    = (const float*)d_in[1];   // [128, 257]
    const float* W     = (const float*)d_in[2];   // [262144, 128]
    const float* bias  = (const float*)d_in[3];   // [262144]
    const float* adapt = (const float*)d_in[4];   // [128]
    int* out = (int*)d_out;                       // [128, 262144] bool -> int32

    double* activity = (double*)d_ws;                              // 262144 f64
    double* adapted  = activity + OUTPUT_SIZE;                     // 128 f64
    unsigned long long* minmax =
        (unsigned long long*)(adapted + N_FILTERS);                // 2 u64
    float* mag = (float*)(minmax + 2);                             // 257 f32

    k1a_dft<<<N_BINS, 64, 0, stream>>>(audio, mag);
    k1b_post<<<1, 256, 0, stream>>>(fb, mag, adapt, adapted, minmax);
    k2_gemv<<<OUTPUT_SIZE / 256, 256, 0, stream>>>(
        (const float4*)W, bias, adapted, activity, minmax);
    k3_spikes<<<dim3(OUTPUT_SIZE / 4 / 256, 4), 256, 0, stream>>>(
        activity, minmax, (int4v*)out);
}

// Round 8
// 304.704 us; speedup vs baseline: 1.4379x; 1.0203x over previous
//
#include <hip/hip_runtime.h>
#include <math.h>

#ifndef M_PI
#define M_PI 3.14159265358979323846
#endif

#define N_FFT       512
#define N_BINS      257
#define N_FILTERS   128
#define OUTPUT_SIZE 262144
#define N_TIMESTEPS 128

typedef int int4v __attribute__((ext_vector_type(4)));

// ---- ordered-uint64 encoding for deterministic double atomic min/max ----
__device__ __forceinline__ unsigned long long enc_d(double f) {
    unsigned long long u = (unsigned long long)__double_as_longlong(f);
    return (u & 0x8000000000000000ull) ? ~u : (u | 0x8000000000000000ull);
}
__device__ __forceinline__ double dec_d(unsigned long long e) {
    unsigned long long u = (e & 0x8000000000000000ull) ? (e ^ 0x8000000000000000ull) : ~e;
    return __longlong_as_double((long long)u);
}

// ============================================================================
// K1a: DFT, one block per bin (257 blocks x 64 threads) — verified round 7.
//   Lane accumulates 8 samples, fp64 sincos twiddles, LDS tree reduce.
//   Block 0 also inits the minmax atomic slots (k2 consumes them later in
//   stream order).
// ============================================================================
__global__ __launch_bounds__(64) void k1a_dft(
    const float* __restrict__ audio, float* __restrict__ mag,
    unsigned long long* __restrict__ minmax)
{
    __shared__ double sre[64];
    __shared__ double sim[64];

    const int b    = blockIdx.x;     // bin 0..256
    const int lane = threadIdx.x;    // 0..63

    double re = 0.0, im = 0.0;
    #pragma unroll
    for (int j = 0; j < 8; ++j) {
        const int n = lane * 8 + j;              // rfft(n=512): first 512 samples
        const int m = (b * n) & (N_FFT - 1);
        double s, c;
        sincos((-2.0 * M_PI * (double)m) / (double)N_FFT, &s, &c);
        const double a = (double)audio[n];
        re += a * c;
        im += a * s;
    }
    sre[lane] = re;
    sim[lane] = im;
    __syncthreads();
    #pragma unroll
    for (int s = 32; s > 0; s >>= 1) {
        if (lane < s) {
            sre[lane] += sre[lane + s];
            sim[lane] += sim[lane + s];
        }
        __syncthreads();
    }
    if (lane == 0) {
        mag[b] = (float)sqrt(sre[0] * sre[0] + sim[0] * sim[0]);
        if (b == 0) {
            minmax[0] = 0xFFFFFFFFFFFFFFFFull;  // min slot
            minmax[1] = 0ull;                   // max slot
        }
    }
}

// ============================================================================
// K2: front-end epilogue (per-block redundant, deterministic) + GEMV.
//   Prologue: every block recomputes adapted[128] from mag/fb/adapt with the
//   EXACT verified sequential fp64 loop + pow — bit-identical across blocks,
//   ~1 us each, removes the former 1-block k1b launch entirely.
//   GEMV: verified round-3 structure — one thread per row, 32 independent
//   float4 loads, sequential fp64 accumulate, LDS min/max tree, one atomic
//   pair per block. (No per-iteration cross-lane ops — round-4 lesson.)
// ============================================================================
__global__ __launch_bounds__(256) void k2_gemv(
    const float4* __restrict__ W4, const float* __restrict__ bias,
    const float* __restrict__ fb, const float* __restrict__ mag,
    const float* __restrict__ adapt, double* __restrict__ activity,
    unsigned long long* __restrict__ minmax)
{
    __shared__ float  magl[N_BINS];
    __shared__ double ad[N_FILTERS];
    __shared__ double red_min[256];
    __shared__ double red_max[256];

    const int tid = threadIdx.x;

    for (int j = tid; j < N_BINS; j += 256) magl[j] = mag[j];
    __syncthreads();

    if (tid < N_FILTERS) {
        double acc = 0.0;
        const float* row = fb + tid * N_BINS;
        #pragma unroll 4
        for (int j = 0; j < N_BINS; ++j)
            acc += (double)row[j] * (double)magl[j];
        const double x = acc + 1e-6;               // + LATENCY_EPSILON
        const double p = pow(x, 0.3);
        const double a = p - (double)adapt[tid] * 0.5;
        ad[tid] = a > 0.0 ? a : 0.0;               // relu
    }
    __syncthreads();

    const int row = blockIdx.x * 256 + tid;
    const float4* wrow = W4 + (size_t)row * (N_FILTERS / 4);

    double acc = 0.0;
    #pragma unroll 8
    for (int j = 0; j < N_FILTERS / 4; ++j) {
        float4 w = wrow[j];
        const int k = j * 4;
        acc += (double)w.x * ad[k];
        acc += (double)w.y * ad[k + 1];
        acc += (double)w.z * ad[k + 2];
        acc += (double)w.w * ad[k + 3];
    }
    double a = acc + (double)bias[row];
    activity[row] = a;

    red_min[tid] = a;
    red_max[tid] = a;
    __syncthreads();
    for (int s = 128; s > 0; s >>= 1) {
        if (tid < s) {
            red_min[tid] = fmin(red_min[tid], red_min[tid + s]);
            red_max[tid] = fmax(red_max[tid], red_max[tid + s]);
        }
        __syncthreads();
    }
    if (tid == 0) {
        atomicMin(&minmax[0], enc_d(red_min[0]));
        atomicMax(&minmax[1], enc_d(red_max[0]));
    }
}

// ============================================================================
// K3: latency coding + spike-matrix write (int32 out), fp64 quantization.
//   PLAIN int4 stores (NT reverted: the harness fill proves plain stores hit
//   6.7 TB/s, and R4 showed W stays L3-resident without NT anyway).
//   t-loop split over gridDim.y=4 -> 1024 blocks; 1 KB/wave/store.
// ============================================================================
__global__ __launch_bounds__(256) void k3_spikes(
    const double* __restrict__ activity,
    const unsigned long long* __restrict__ minmax,
    int4v* __restrict__ out4)
{
    const int tid = blockIdx.x * 256 + threadIdx.x;  // 0..65535
    const double amin = dec_d(minmax[0]);
    const double amax = dec_d(minmax[1]);
    const double denom = (amax - amin) + 1e-6;

    const double nx = (activity[4 * tid + 0] - amin) / denom;
    const double ny = (activity[4 * tid + 1] - amin) / denom;
    const double nz = (activity[4 * tid + 2] - amin) / denom;
    const double nw = (activity[4 * tid + 3] - amin) / denom;

    const int lx = (int)((1.0 - nx) * 127.0);
    const int ly = (int)((1.0 - ny) * 127.0);
    const int lz = (int)((1.0 - nz) * 127.0);
    const int lw = (int)((1.0 - nw) * 127.0);

    const int vx = (nx > 0.05) ? 1 : 0;
    const int vy = (ny > 0.05) ? 1 : 0;
    const int vz = (nz > 0.05) ? 1 : 0;
    const int vw = (nw > 0.05) ? 1 : 0;

    const int t0 = blockIdx.y * (N_TIMESTEPS / 4);
    #pragma unroll 8
    for (int t = t0; t < t0 + N_TIMESTEPS / 4; ++t) {
        int4v v;
        v.x = (lx == t) ? vx : 0;
        v.y = (ly == t) ? vy : 0;
        v.z = (lz == t) ? vz : 0;
        v.w = (lw == t) ? vw : 0;
        out4[(size_t)t * (OUTPUT_SIZE / 4) + tid] = v;
    }
}

// ============================================================================
extern "C" void kernel_launch(void* const* d_in, const int* in_sizes, int n_in,
                              void* d_out, int out_size, void* d_ws, size_t ws_size,
                              hipStream_t stream) {
    (void)in_sizes; (void)n_in; (void)out_size; (void)ws_size;

    const float* audio = (const float*)d_in[0];   // [16000]
    const float* fb    = (const float*)d_in[1];   // [128, 257]
    const float* W     = (const float*)d_in[2];   // [262144, 128]
    const float* bias  = (const float*)d_in[3];   // [262144]
    const float* adapt = (const float*)d_in[4];   // [128]
    int* out = (int*)d_out;                       // [128, 262144] bool -> int32

    double* activity = (double*)d_ws;                              // 262144 f64
    unsigned long long* minmax =
        (unsigned long long*)(activity + OUTPUT_SIZE);             // 2 u64
    float* mag = (float*)(minmax + 2);                             // 257 f32

    k1a_dft<<<N_BINS, 64, 0, stream>>>(audio, mag, minmax);
    k2_gemv<<<OUTPUT_SIZE / 256, 256, 0, stream>>>(
        (const float4*)W, bias, fb, mag, adapt, activity, minmax);
    k3_spikes<<<dim3(OUTPUT_SIZE / 4 / 256, 4), 256, 0, stream>>>(
        activity, minmax, (int4v*)out);
}